// Round 25
// baseline (184.971 us; speedup 1.0000x reference)
//
#include <hip/hip_runtime.h>
#include <hip/hip_bf16.h>
#include <hip/hip_fp16.h>

#define NPTS 200000
#define NVOX 60000
#define NB 4
#define KK 27
#define NTILE 1875          // NVOX/32
#define TPB 2               // tiles per block in k_conv2

typedef short bf16x8 __attribute__((ext_vector_type(8)));
typedef float f32x4 __attribute__((ext_vector_type(4)));

__device__ __forceinline__ bf16x8 as_bf16x8(uint4 u) {
    union { uint4 a; bf16x8 b; } x; x.a = u; return x.b;
}

// ---- mask encoding: 0 = uint8 bool, 1 = int32, 2 = float32 ----
__device__ __forceinline__ float get_mask(const void* nm, int fl, long i) {
    if (fl == 0) return ((const unsigned char*)nm)[i] ? 1.0f : 0.0f;
    if (fl == 1) return ((const int*)nm)[i] ? 1.0f : 0.0f;
    return ((const float*)nm)[i];
}

// bf16 helpers: RNE pack
__device__ __forceinline__ unsigned bf16rn(float f) {
    unsigned u = __float_as_uint(f);
    u += 0x7fffu + ((u >> 16) & 1u);
    return u >> 16;
}

// ---- init: zero scratch + pack W2 -> bf16 TRANSPOSED [k][cout][cin] + detect mask ----
__global__ void k_init(float* zbase, int nz, const unsigned int* nm, int* flag,
                       const float* __restrict__ W2, unsigned* __restrict__ W2tb) {
    int t0 = blockIdx.x * 256 + threadIdx.x;
    for (int i = t0; i < nz; i += gridDim.x * 256)
        zbase[i] = 0.f;
    // W2tb[k*512 + n*16 + c/2] = bf16(W2[k][c][n]) | bf16(W2[k][c+1][n])<<16
    for (int i = t0; i < KK * 512; i += gridDim.x * 256) {
        int k = i >> 9, r = i & 511, n = r >> 4, cp = r & 15;
        const float* wsrc = W2 + k * 1024;
        unsigned lo = bf16rn(wsrc[(2 * cp) * 32 + n]);
        unsigned hi = bf16rn(wsrc[(2 * cp + 1) * 32 + n]);
        W2tb[i] = lo | (hi << 16);
    }
    if (blockIdx.x == 0) {
        __shared__ int cntF, cntI;
        if (threadIdx.x == 0) { cntF = 0; cntI = 0; }
        __syncthreads();
        int f = 0, i1 = 0;
        for (int i = threadIdx.x; i < 1024; i += 256) {
            unsigned int v = nm[i];
            if (v == 0x3f800000u) f++;
            if (v == 1u) i1++;
        }
        atomicAdd(&cntF, f); atomicAdd(&cntI, i1);
        __syncthreads();
        if (threadIdx.x == 0)
            *flag = (cntF > 100) ? 2 : ((cntI > 100) ? 1 : 0);
    }
}

// ---- voxelize: scatter-add via packed-f16 atomics (3 atomics/point) ----
__global__ void k_scatter(const float4* __restrict__ feat, const int* __restrict__ p2v,
                          float* cnt, __half2* voxh) {
    int p = blockIdx.x * 256 + threadIdx.x;
    if (p >= NPTS) return;
    int v = p2v[p];
    float4 f = feat[p];
    atomicAdd(&cnt[v], 1.0f);
    unsafeAtomicAdd(&voxh[v * 2 + 0], __floats2half2_rn(f.x, f.y));
    unsafeAtomicAdd(&voxh[v * 2 + 1], __floats2half2_rn(f.z, f.w));
}

// ---- voxdiv: f16 sums -> f32 averages ----
__global__ void k_voxdiv(const __half2* __restrict__ voxh, float* vox,
                         const float* __restrict__ cnt) {
    int n = blockIdx.x * 256 + threadIdx.x;
    if (n >= NVOX) return;
    float inv = 1.0f / fmaxf(cnt[n], 1.0f);
    float2 ab = __half22float2(voxh[n * 2 + 0]);
    float2 cd = __half22float2(voxh[n * 2 + 1]);
    float4 v = make_float4(ab.x * inv, ab.y * inv, cd.x * inv, cd.y * inv);
    ((float4*)vox)[n] = v;
}

// ---- conv1: Cin=4 -> Cout=32; 256 thr = 64 vox x 4 kc-waves; h1 OUT in bf16 ----
__global__ __launch_bounds__(256) void k_conv1(
        const float* __restrict__ vox, const float* __restrict__ W1,
        const float* __restrict__ g1, const float* __restrict__ b1,
        const int* __restrict__ nidx, const void* __restrict__ nmask,
        const int* __restrict__ flag, unsigned* __restrict__ h1b) {
    __shared__ float part[3][64][33];
    int tid = threadIdx.x;
    int lane = tid & 63;
    int kc = __builtin_amdgcn_readfirstlane(tid >> 6);   // wave-uniform chunk
    int v = blockIdx.x * 64 + lane;
    int vc = v < NVOX ? v : NVOX - 1;
    int fl = *flag;
    int k0 = kc * 7;
    int k1 = (kc == 3) ? KK : k0 + 7;   // 7,7,7,6
    float acc[32];
#pragma unroll
    for (int d = 0; d < 32; d++) acc[d] = 0.f;
#pragma unroll 2
    for (int k = k0; k < k1; ++k) {
        int idx = nidx[k * NVOX + vc];
        float m = get_mask(nmask, fl, (long)k * NVOX + vc);
        float4 r = ((const float4*)vox)[idx];
        const float* wk = W1 + k * 128;   // wave-uniform -> s_load (3.4KB, K$-resident)
#pragma unroll
        for (int c = 0; c < 4; c++) {
            float rc = (c == 0 ? r.x : c == 1 ? r.y : c == 2 ? r.z : r.w) * m;
            const float* wc = wk + c * 32;
#pragma unroll
            for (int d = 0; d < 32; d++) acc[d] = fmaf(rc, wc[d], acc[d]);
        }
    }
    if (kc > 0) {
#pragma unroll
        for (int d = 0; d < 32; d++) part[kc - 1][lane][d] = acc[d];
    }
    __syncthreads();
    if (kc == 0 && v < NVOX) {
        unsigned pk[16];
#pragma unroll
        for (int i = 0; i < 16; i++) {
            float e0 = acc[2 * i]     + part[0][lane][2 * i]     + part[1][lane][2 * i]     + part[2][lane][2 * i];
            float e1 = acc[2 * i + 1] + part[0][lane][2 * i + 1] + part[1][lane][2 * i + 1] + part[2][lane][2 * i + 1];
            float o0 = fmaxf(e0 * g1[2 * i] + b1[2 * i], 0.f);
            float o1 = fmaxf(e1 * g1[2 * i + 1] + b1[2 * i + 1], 0.f);
            pk[i] = bf16rn(o0) | (bf16rn(o1) << 16);
        }
        uint4* op = (uint4*)(h1b + (size_t)v * 16);   // 64B row
#pragma unroll
        for (int qq = 0; qq < 4; qq++)
            op[qq] = make_uint4(pk[qq * 4], pk[qq * 4 + 1], pk[qq * 4 + 2], pk[qq * 4 + 3]);
    }
}

// ---- conv2 via MFMA: BURST gather (named regs a0..a13) then MFMA sweep ----
// r24: VGPR=48, time unchanged -> compiler still interleaves gather/MFMA serially.
// Force it: straight-line named-register loads for all 14 rows (no arrays),
// THEN 28 MFMAs. Live ~90 VGPR, no runtime indexing -> no scratch.
__global__ __launch_bounds__(256) void k_conv2(
        const unsigned* __restrict__ h1b, const unsigned* __restrict__ W2tb,
        const float* __restrict__ g2, const float* __restrict__ b2,
        const int* __restrict__ nidx, const void* __restrict__ nmask,
        const int* __restrict__ flag, float* __restrict__ h2,
        const int* __restrict__ vb,
        float* bsum, unsigned int* bmax, float* bcnt) {
    __shared__ float part[2][64][8];   // kc=1 partials, 4KB (reused per tile)
    __shared__ float ls[NB * 32];
    __shared__ unsigned lm[NB * 32];
    __shared__ float lc[NB];
    int tid = threadIdx.x;
    if (tid < NB * 32) { ls[tid] = 0.f; lm[tid] = 0u; }
    if (tid < NB) lc[tid] = 0.f;
    __syncthreads();
    int l = tid & 63;
    int w = tid >> 6;
    int t  = __builtin_amdgcn_readfirstlane(w & 1);    // vox tile half
    int kc = __builtin_amdgcn_readfirstlane(w >> 1);   // k half
    int col = l & 15;                                  // cout (and A vox row)
    int kgrp = l >> 4;                                 // cin slice
    int fl = *flag;
    int k0 = kc ? 14 : 0;
    int k1 = kc ? KK : 14;   // 13 or 14 valid iterations

#pragma unroll 1
    for (int tile = 0; tile < TPB; ++tile) {
        int ti = blockIdx.x * TPB + tile;
        bool active = ti < NTILE;                      // block-uniform
        int vbase = ti * 32 + t * 16;
        int vrow = vbase + col;
        f32x4 acc0 = {0.f, 0.f, 0.f, 0.f};
        f32x4 acc1 = {0.f, 0.f, 0.f, 0.f};
        if (active) {
            // Phase 1: preload all k indices (independent, coalesced)
            int pidx[14];
#pragma unroll
            for (int j = 0; j < 14; ++j) {
                int k = k0 + j;
                bool ok = k < k1;
                int kk = ok ? k : k0;
                int idx = nidx[kk * NVOX + vrow];
                float m = get_mask(nmask, fl, (long)kk * NVOX + vrow);
                pidx[j] = (ok && m != 0.f) ? idx : -1;
            }
            // Phase 2a: BURST — all 14 row gathers into named registers
#define GATH(J) uint4 a##J = make_uint4(0u,0u,0u,0u); \
    if (pidx[J] >= 0) a##J = ((const uint4*)(h1b + (size_t)pidx[J] * 16))[kgrp];
            GATH(0) GATH(1) GATH(2) GATH(3) GATH(4) GATH(5) GATH(6)
            GATH(7) GATH(8) GATH(9) GATH(10) GATH(11) GATH(12) GATH(13)
#undef GATH
            // Phase 2b: MFMA sweep (weights L1/L2-hot; k clamped so B is valid)
#define MM(J) { \
    int kw = (k0 + J < KK) ? (k0 + J) : 0; \
    const uint4* wt = (const uint4*)(W2tb + kw * 512); \
    uint4 bA = wt[col * 4 + kgrp]; \
    uint4 bB = wt[(col + 16) * 4 + kgrp]; \
    bf16x8 av = as_bf16x8(a##J); \
    acc0 = __builtin_amdgcn_mfma_f32_16x16x32_bf16(av, as_bf16x8(bA), acc0, 0, 0, 0); \
    acc1 = __builtin_amdgcn_mfma_f32_16x16x32_bf16(av, as_bf16x8(bB), acc1, 0, 0, 0); }
            MM(0) MM(1) MM(2) MM(3) MM(4) MM(5) MM(6)
            MM(7) MM(8) MM(9) MM(10) MM(11) MM(12) MM(13)
#undef MM
            if (kc == 1) {
#pragma unroll
                for (int r = 0; r < 4; r++) {
                    part[t][l][r]     = acc0[r];
                    part[t][l][4 + r] = acc1[r];
                }
            }
        }
        __syncthreads();
        if (active && kc == 0) {
#pragma unroll
            for (int r = 0; r < 4; r++) {
                acc0[r] += part[t][l][r];
                acc1[r] += part[t][l][4 + r];
            }
            float ga = g2[col],      ba = b2[col];
            float gb = g2[col + 16], bb_ = b2[col + 16];
#pragma unroll
            for (int r = 0; r < 4; r++) {
                int vox = vbase + kgrp * 4 + r;
                float o0 = fmaxf(acc0[r] * ga + ba, 0.f);
                float o1 = fmaxf(acc1[r] * gb + bb_, 0.f);
                h2[(size_t)vox * 32 + col]      = o0;
                h2[(size_t)vox * 32 + 16 + col] = o1;
                int b = vb[vox];
                atomicAdd(&ls[b * 32 + col], o0);
                atomicAdd(&ls[b * 32 + 16 + col], o1);
                atomicMax(&lm[b * 32 + col], __float_as_uint(o0));       // o >= 0
                atomicMax(&lm[b * 32 + 16 + col], __float_as_uint(o1));
                if (col == 0) atomicAdd(&lc[b], 1.f);
            }
        }
        __syncthreads();   // part[] safe for next tile
    }
    if (tid < NB * 32) {
        atomicAdd(&bsum[tid], ls[tid]);
        atomicMax(&bmax[tid], lm[tid]);
    }
    if (tid < NB) atomicAdd(&bcnt[tid], lc[tid]);
}

// ---- apply channel attention + build s2; CA-MLP fused ----
__global__ void k_apply(float* h2,
                        const float* __restrict__ bsum, const unsigned int* __restrict__ bmax,
                        const float* __restrict__ bcnt,
                        const float* __restrict__ caw1, const float* __restrict__ cab1,
                        const float* __restrict__ caw2, const float* __restrict__ cab2,
                        const int* __restrict__ vb, float* __restrict__ s2) {
    __shared__ float cas[NB * 32];
    if (threadIdx.x < NB) {
        int b = threadIdx.x;
        float avg[32], mx[32], o[32];
        float inv = 1.0f / fmaxf(bcnt[b], 1.0f);
#pragma unroll
        for (int c = 0; c < 32; c++) {
            avg[c] = bsum[b * 32 + c] * inv;
            mx[c]  = __uint_as_float(bmax[b * 32 + c]);
            o[c] = 0.f;
        }
#pragma unroll
        for (int pass = 0; pass < 2; pass++) {
            float r[8];
#pragma unroll
            for (int j = 0; j < 8; j++) {
                float s = cab1[j];
#pragma unroll
                for (int c = 0; c < 32; c++) s += (pass ? mx[c] : avg[c]) * caw1[c * 8 + j];
                r[j] = fmaxf(s, 0.f);
            }
#pragma unroll
            for (int d = 0; d < 32; d++) {
                float s = cab2[d];
#pragma unroll
                for (int j = 0; j < 8; j++) s += r[j] * caw2[j * 32 + d];
                o[d] += s;
            }
        }
#pragma unroll
        for (int d = 0; d < 32; d++)
            cas[b * 32 + d] = 1.0f / (1.0f + expf(-o[d]));
    }
    __syncthreads();
    int t = blockIdx.x * 256 + threadIdx.x;
    int v = t >> 1, hf = t & 1;
    if (v >= NVOX) return;
    int b = vb[v];
    float4* hp = (float4*)(h2 + (size_t)v * 32) + hf * 4;
    const float4* cp = (const float4*)(cas + b * 32) + hf * 4;
    float sum = 0.f, mx = 0.f;
#pragma unroll
    for (int q = 0; q < 4; q++) {
        float4 h = hp[q]; float4 c = cp[q];
        h.x *= c.x; h.y *= c.y; h.z *= c.z; h.w *= c.w;
        hp[q] = h;
        sum += h.x + h.y + h.z + h.w;
        mx = fmaxf(mx, fmaxf(fmaxf(h.x, h.y), fmaxf(h.z, h.w)));
    }
    sum += __shfl_xor(sum, 1);
    mx = fmaxf(mx, __shfl_xor(mx, 1));
    if (hf == 0) {
        s2[v * 2 + 0] = sum * (1.0f / 32.0f);
        s2[v * 2 + 1] = mx;
    }
}

// ---- spatial attention: 2-ch sparse conv -> sigmoid; 4 thr/voxel ----
__global__ void k_saconv(const float* __restrict__ s2, const float* __restrict__ saW,
                         const int* __restrict__ nidx, const void* __restrict__ nmask,
                         const int* __restrict__ flag, float* __restrict__ sa) {
    __shared__ float w[KK * 2];
    if (threadIdx.x < KK * 2) w[threadIdx.x] = saW[threadIdx.x];
    __syncthreads();
    int t = blockIdx.x * 256 + threadIdx.x;
    int v = t >> 2, q = t & 3;
    if (v >= NVOX) return;
    int fl = *flag;
    float acc = 0.f;
#pragma unroll
    for (int j = 0; j < 7; j++) {
        int k = q + j * 4;
        if (k < KK) {
            int idx = nidx[k * NVOX + v];
            float m = get_mask(nmask, fl, (long)k * NVOX + v);
            float2 s = ((const float2*)s2)[idx];
            acc += m * (s.x * w[k * 2] + s.y * w[k * 2 + 1]);
        }
    }
    acc += __shfl_xor(acc, 1);
    acc += __shfl_xor(acc, 2);
    if (q == 0) sa[v] = 1.0f / (1.0f + expf(-acc));
}

// ---- gather to points, apply sa, classifier; 2 thr/point; coalesced stores ----
__global__ __launch_bounds__(256) void k_final(
        const float* __restrict__ h2, const float* __restrict__ sa,
        const int* __restrict__ p2v, const float* __restrict__ clsw,
        const float* __restrict__ clsb, float* __restrict__ out) {
    __shared__ float w[32 * 20];
    __shared__ float bb[20];
    for (int i = threadIdx.x; i < 640; i += 256) w[i] = clsw[i];
    if (threadIdx.x < 20) bb[threadIdx.x] = clsb[threadIdx.x];
    __syncthreads();
    int t = blockIdx.x * 256 + threadIdx.x;
    int p = t >> 1, ch = t & 1;
    if (p >= NPTS) return;
    int v = p2v[p];
    float s = sa[v];
    float acc[20];
#pragma unroll
    for (int j = 0; j < 20; j++) acc[j] = 0.f;
    const float4* hp = (const float4*)(h2 + (size_t)v * 32) + ch * 4;
#pragma unroll
    for (int q = 0; q < 4; q++) {
        float4 h = hp[q];
        int cb = (ch * 16 + q * 4) * 20;
        float z0 = h.x * s, z1 = h.y * s, z2 = h.z * s, z3 = h.w * s;
#pragma unroll
        for (int j = 0; j < 20; j++)
            acc[j] += z0 * w[cb + j] + z1 * w[cb + 20 + j]
                    + z2 * w[cb + 40 + j] + z3 * w[cb + 60 + j];
    }
#pragma unroll
    for (int j = 0; j < 20; j++) acc[j] += __shfl_xor(acc[j], 1);
    // both lanes hold the full sums: each stores its own 10 contiguous floats
    float* op = out + (size_t)p * 20;
    if (ch == 0) {
#pragma unroll
        for (int j = 0; j < 5; j++)
            ((float2*)op)[j] = make_float2(acc[2 * j] + bb[2 * j],
                                           acc[2 * j + 1] + bb[2 * j + 1]);
    } else {
#pragma unroll
        for (int j = 0; j < 5; j++)
            ((float2*)(op + 10))[j] = make_float2(acc[10 + 2 * j] + bb[10 + 2 * j],
                                                  acc[11 + 2 * j] + bb[11 + 2 * j]);
    }
}

extern "C" void kernel_launch(void* const* d_in, const int* in_sizes, int n_in,
                              void* d_out, int out_size, void* d_ws, size_t ws_size,
                              hipStream_t stream) {
    const float* feat = (const float*)d_in[0];
    const float* W1   = (const float*)d_in[1];
    const float* g1   = (const float*)d_in[2];
    const float* b1   = (const float*)d_in[3];
    const float* W2   = (const float*)d_in[4];
    const float* g2   = (const float*)d_in[5];
    const float* b2   = (const float*)d_in[6];
    const float* caw1 = (const float*)d_in[7];
    const float* cab1 = (const float*)d_in[8];
    const float* caw2 = (const float*)d_in[9];
    const float* cab2 = (const float*)d_in[10];
    const float* saW  = (const float*)d_in[11];
    const float* clsw = (const float*)d_in[12];
    const float* clsb = (const float*)d_in[13];
    const int* p2v    = (const int*)d_in[14];
    const int* vb     = (const int*)d_in[15];
    const int* nidx   = (const int*)d_in[16];
    const void* nmask = d_in[17];
    float* out = (float*)d_out;

    int* flag   = (int*)d_ws;
    float* cnt  = (float*)d_ws + 64;              // 60000
    __half2* voxh = (__half2*)(cnt + NVOX);       // NVOX*2 half2 = 120000 f32-slots
    float* vox  = (float*)(voxh) + NVOX * 2;      // f32 averages (240000)
    float* bsum = vox + (size_t)NVOX * 4;         // 128
    unsigned int* bmax = (unsigned int*)(bsum + NB * 32);  // 128
    float* bcnt = (float*)(bmax + NB * 32);       // 4
    float* ca   = bcnt + 64;                      // 128 (unused now, kept for layout)
    unsigned* W2tb = (unsigned*)(ca + 128);       // 13824 u32 bf16 W2^T (+pad)
    unsigned* h1b = W2tb + 14336;                 // bf16-packed h1: NVOX*16 uints
    float* h2   = (float*)(h1b + (size_t)NVOX * 16);
    float* s2   = h2 + (size_t)NVOX * 32;
    float* sa   = s2 + (size_t)NVOX * 2;

    // zero cnt + voxh + (vox) + bsum/bmax/bcnt/ca region
    int nzero = NVOX * 7 + NB * 32 * 2 + NB + 64;
    k_init<<<512, 256, 0, stream>>>(cnt, nzero, (const unsigned int*)nmask, flag, W2, W2tb);
    k_scatter<<<(NPTS + 255) / 256, 256, 0, stream>>>((const float4*)feat, p2v, cnt, voxh);
    k_voxdiv<<<(NVOX + 255) / 256, 256, 0, stream>>>(voxh, vox, cnt);
    k_conv1<<<(NVOX + 63) / 64, 256, 0, stream>>>(vox, W1, g1, b1, nidx, nmask, flag, h1b);
    k_conv2<<<(NTILE + TPB - 1) / TPB, 256, 0, stream>>>(h1b, W2tb, g2, b2, nidx, nmask,
                                                         flag, h2, vb, bsum, bmax, bcnt);
    k_apply<<<(NVOX * 2 + 255) / 256, 256, 0, stream>>>(h2, bsum, bmax, bcnt,
                                                        caw1, cab1, caw2, cab2, vb, s2);
    k_saconv<<<(NVOX * 4 + 255) / 256, 256, 0, stream>>>(s2, saW, nidx, nmask, flag, sa);
    k_final<<<(NPTS * 2 + 255) / 256, 256, 0, stream>>>(h2, sa, p2v, clsw, clsb, out);
}

// Round 26
// 172.400 us; speedup vs baseline: 1.0729x; 1.0729x over previous
//
#include <hip/hip_runtime.h>
#include <hip/hip_bf16.h>
#include <hip/hip_fp16.h>

#define NPTS 200000
#define NVOX 60000
#define NB 4
#define KK 27
#define NTILE 1875          // NVOX/32

typedef short bf16x8 __attribute__((ext_vector_type(8)));
typedef float f32x4 __attribute__((ext_vector_type(4)));

__device__ __forceinline__ bf16x8 as_bf16x8(uint4 u) {
    union { uint4 a; bf16x8 b; } x; x.a = u; return x.b;
}

// ---- mask encoding: 0 = uint8 bool, 1 = int32, 2 = float32 ----
__device__ __forceinline__ float get_mask(const void* nm, int fl, long i) {
    if (fl == 0) return ((const unsigned char*)nm)[i] ? 1.0f : 0.0f;
    if (fl == 1) return ((const int*)nm)[i] ? 1.0f : 0.0f;
    return ((const float*)nm)[i];
}

// bf16 helpers: RNE pack
__device__ __forceinline__ unsigned bf16rn(float f) {
    unsigned u = __float_as_uint(f);
    u += 0x7fffu + ((u >> 16) & 1u);
    return u >> 16;
}

// ---- init: zero scratch + pack W2 -> bf16 TRANSPOSED [k][cout][cin] + detect mask ----
__global__ void k_init(float* zbase, int nz, const unsigned int* nm, int* flag,
                       const float* __restrict__ W2, unsigned* __restrict__ W2tb) {
    int t0 = blockIdx.x * 256 + threadIdx.x;
    for (int i = t0; i < nz; i += gridDim.x * 256)
        zbase[i] = 0.f;
    // W2tb[k*512 + n*16 + c/2] = bf16(W2[k][c][n]) | bf16(W2[k][c+1][n])<<16
    for (int i = t0; i < KK * 512; i += gridDim.x * 256) {
        int k = i >> 9, r = i & 511, n = r >> 4, cp = r & 15;
        const float* wsrc = W2 + k * 1024;
        unsigned lo = bf16rn(wsrc[(2 * cp) * 32 + n]);
        unsigned hi = bf16rn(wsrc[(2 * cp + 1) * 32 + n]);
        W2tb[i] = lo | (hi << 16);
    }
    if (blockIdx.x == 0) {
        __shared__ int cntF, cntI;
        if (threadIdx.x == 0) { cntF = 0; cntI = 0; }
        __syncthreads();
        int f = 0, i1 = 0;
        for (int i = threadIdx.x; i < 1024; i += 256) {
            unsigned int v = nm[i];
            if (v == 0x3f800000u) f++;
            if (v == 1u) i1++;
        }
        atomicAdd(&cntF, f); atomicAdd(&cntI, i1);
        __syncthreads();
        if (threadIdx.x == 0)
            *flag = (cntF > 100) ? 2 : ((cntI > 100) ? 1 : 0);
    }
}

// ---- voxelize: scatter-add via packed-f16 atomics (3 atomics/point) ----
__global__ void k_scatter(const float4* __restrict__ feat, const int* __restrict__ p2v,
                          float* cnt, __half2* voxh) {
    int p = blockIdx.x * 256 + threadIdx.x;
    if (p >= NPTS) return;
    int v = p2v[p];
    float4 f = feat[p];
    atomicAdd(&cnt[v], 1.0f);
    unsafeAtomicAdd(&voxh[v * 2 + 0], __floats2half2_rn(f.x, f.y));
    unsafeAtomicAdd(&voxh[v * 2 + 1], __floats2half2_rn(f.z, f.w));
}

// ---- voxdiv: f16 sums -> f32 averages ----
__global__ void k_voxdiv(const __half2* __restrict__ voxh, float* vox,
                         const float* __restrict__ cnt) {
    int n = blockIdx.x * 256 + threadIdx.x;
    if (n >= NVOX) return;
    float inv = 1.0f / fmaxf(cnt[n], 1.0f);
    float2 ab = __half22float2(voxh[n * 2 + 0]);
    float2 cd = __half22float2(voxh[n * 2 + 1]);
    float4 v = make_float4(ab.x * inv, ab.y * inv, cd.x * inv, cd.y * inv);
    ((float4*)vox)[n] = v;
}

// ---- conv1: Cin=4 -> Cout=32; 256 thr = 64 vox x 4 kc-waves; h1 OUT in bf16 ----
__global__ __launch_bounds__(256) void k_conv1(
        const float* __restrict__ vox, const float* __restrict__ W1,
        const float* __restrict__ g1, const float* __restrict__ b1,
        const int* __restrict__ nidx, const void* __restrict__ nmask,
        const int* __restrict__ flag, unsigned* __restrict__ h1b) {
    __shared__ float part[3][64][33];
    int tid = threadIdx.x;
    int lane = tid & 63;
    int kc = __builtin_amdgcn_readfirstlane(tid >> 6);   // wave-uniform chunk
    int v = blockIdx.x * 64 + lane;
    int vc = v < NVOX ? v : NVOX - 1;
    int fl = *flag;
    int k0 = kc * 7;
    int k1 = (kc == 3) ? KK : k0 + 7;   // 7,7,7,6
    float acc[32];
#pragma unroll
    for (int d = 0; d < 32; d++) acc[d] = 0.f;
#pragma unroll 2
    for (int k = k0; k < k1; ++k) {
        int idx = nidx[k * NVOX + vc];
        float m = get_mask(nmask, fl, (long)k * NVOX + vc);
        float4 r = ((const float4*)vox)[idx];
        const float* wk = W1 + k * 128;   // wave-uniform -> s_load (3.4KB, K$-resident)
#pragma unroll
        for (int c = 0; c < 4; c++) {
            float rc = (c == 0 ? r.x : c == 1 ? r.y : c == 2 ? r.z : r.w) * m;
            const float* wc = wk + c * 32;
#pragma unroll
            for (int d = 0; d < 32; d++) acc[d] = fmaf(rc, wc[d], acc[d]);
        }
    }
    if (kc > 0) {
#pragma unroll
        for (int d = 0; d < 32; d++) part[kc - 1][lane][d] = acc[d];
    }
    __syncthreads();
    if (kc == 0 && v < NVOX) {
        unsigned pk[16];
#pragma unroll
        for (int i = 0; i < 16; i++) {
            float e0 = acc[2 * i]     + part[0][lane][2 * i]     + part[1][lane][2 * i]     + part[2][lane][2 * i];
            float e1 = acc[2 * i + 1] + part[0][lane][2 * i + 1] + part[1][lane][2 * i + 1] + part[2][lane][2 * i + 1];
            float o0 = fmaxf(e0 * g1[2 * i] + b1[2 * i], 0.f);
            float o1 = fmaxf(e1 * g1[2 * i + 1] + b1[2 * i + 1], 0.f);
            pk[i] = bf16rn(o0) | (bf16rn(o1) << 16);
        }
        uint4* op = (uint4*)(h1b + (size_t)v * 16);   // 64B row
#pragma unroll
        for (int qq = 0; qq < 4; qq++)
            op[qq] = make_uint4(pk[qq * 4], pk[qq * 4 + 1], pk[qq * 4 + 2], pk[qq * 4 + 3]);
    }
}

// ---- conv2 via MFMA: 512 thr = 8 waves = 2 CONCURRENT tiles x (2 vox-half x 2 kc) ----
// r25 burst (VGPR 72 > 64-step) regressed: reverted to r24 loop (VGPR 48).
// r24 was grid-limited (3752 waves = 3.7/SIMD offered, 27% occ). Concurrent tiles
// double waves/block at same grid: 7504 waves = 7.3/SIMD offered, VGPR<=64 allows 8.
__global__ __launch_bounds__(512) void k_conv2(
        const unsigned* __restrict__ h1b, const unsigned* __restrict__ W2tb,
        const float* __restrict__ g2, const float* __restrict__ b2,
        const int* __restrict__ nidx, const void* __restrict__ nmask,
        const int* __restrict__ flag, float* __restrict__ h2,
        const int* __restrict__ vb,
        float* bsum, unsigned int* bmax, float* bcnt) {
    __shared__ float part[2][2][64][8];   // [tile-group][vox-half] partials, 8KB
    __shared__ float ls[NB * 32];
    __shared__ unsigned lm[NB * 32];
    __shared__ float lc[NB];
    int tid = threadIdx.x;
    if (tid < NB * 32) { ls[tid] = 0.f; lm[tid] = 0u; }
    if (tid < NB) lc[tid] = 0.f;
    __syncthreads();
    int l = tid & 63;
    int w = tid >> 6;                                   // 0..7
    int tg = __builtin_amdgcn_readfirstlane(w >> 2);    // concurrent tile 0/1
    int t  = __builtin_amdgcn_readfirstlane(w & 1);     // vox tile half
    int kc = __builtin_amdgcn_readfirstlane((w >> 1) & 1);  // k half
    int col = l & 15;                                   // cout (and A vox row)
    int kgrp = l >> 4;                                  // cin slice
    int fl = *flag;
    int k0 = kc ? 14 : 0;
    int k1 = kc ? KK : 14;   // 13 or 14 valid iterations

    int ti = blockIdx.x * 2 + tg;
    bool active = ti < NTILE;                           // wave-uniform
    int vbase = ti * 32 + t * 16;
    int vrow = vbase + col;
    f32x4 acc0 = {0.f, 0.f, 0.f, 0.f};
    f32x4 acc1 = {0.f, 0.f, 0.f, 0.f};
    if (active) {
        // Phase 1: preload all k indices (independent, coalesced)
        int pidx[14];
#pragma unroll
        for (int j = 0; j < 14; ++j) {
            int k = k0 + j;
            bool ok = k < k1;
            int kk = ok ? k : k0;
            int idx = nidx[kk * NVOX + vrow];
            float m = get_mask(nmask, fl, (long)kk * NVOX + vrow);
            pidx[j] = (ok && m != 0.f) ? idx : -1;
        }
        // Phase 2: register-indexed gathers + MFMA
#pragma unroll
        for (int j = 0; j < 14; ++j) {
            int pi = pidx[j];
            uint4 a = make_uint4(0u, 0u, 0u, 0u);
            if (pi >= 0)
                a = ((const uint4*)(h1b + (size_t)pi * 16))[kgrp];
            int kw = (k0 + j < KK) ? (k0 + j) : 0;   // clamp: no garbage B
            const uint4* wt = (const uint4*)(W2tb + kw * 512);
            uint4 bA = wt[col * 4 + kgrp];          // cout = col
            uint4 bB = wt[(col + 16) * 4 + kgrp];   // cout = col+16
            bf16x8 av = as_bf16x8(a);
            acc0 = __builtin_amdgcn_mfma_f32_16x16x32_bf16(av, as_bf16x8(bA), acc0, 0, 0, 0);
            acc1 = __builtin_amdgcn_mfma_f32_16x16x32_bf16(av, as_bf16x8(bB), acc1, 0, 0, 0);
        }
        if (kc == 1) {
#pragma unroll
            for (int r = 0; r < 4; r++) {
                part[tg][t][l][r]     = acc0[r];
                part[tg][t][l][4 + r] = acc1[r];
            }
        }
    }
    __syncthreads();
    if (active && kc == 0) {
#pragma unroll
        for (int r = 0; r < 4; r++) {
            acc0[r] += part[tg][t][l][r];
            acc1[r] += part[tg][t][l][4 + r];
        }
        float ga = g2[col],      ba = b2[col];
        float gb = g2[col + 16], bb_ = b2[col + 16];
#pragma unroll
        for (int r = 0; r < 4; r++) {
            int vox = vbase + kgrp * 4 + r;
            float o0 = fmaxf(acc0[r] * ga + ba, 0.f);
            float o1 = fmaxf(acc1[r] * gb + bb_, 0.f);
            h2[(size_t)vox * 32 + col]      = o0;
            h2[(size_t)vox * 32 + 16 + col] = o1;
            int b = vb[vox];
            atomicAdd(&ls[b * 32 + col], o0);
            atomicAdd(&ls[b * 32 + 16 + col], o1);
            atomicMax(&lm[b * 32 + col], __float_as_uint(o0));       // o >= 0
            atomicMax(&lm[b * 32 + 16 + col], __float_as_uint(o1));
            if (col == 0) atomicAdd(&lc[b], 1.f);
        }
    }
    __syncthreads();
    if (tid < NB * 32) {
        atomicAdd(&bsum[tid], ls[tid]);
        atomicMax(&bmax[tid], lm[tid]);
    }
    if (tid < NB) atomicAdd(&bcnt[tid], lc[tid]);
}

// ---- apply channel attention + build s2; CA-MLP fused ----
__global__ void k_apply(float* h2,
                        const float* __restrict__ bsum, const unsigned int* __restrict__ bmax,
                        const float* __restrict__ bcnt,
                        const float* __restrict__ caw1, const float* __restrict__ cab1,
                        const float* __restrict__ caw2, const float* __restrict__ cab2,
                        const int* __restrict__ vb, float* __restrict__ s2) {
    __shared__ float cas[NB * 32];
    if (threadIdx.x < NB) {
        int b = threadIdx.x;
        float avg[32], mx[32], o[32];
        float inv = 1.0f / fmaxf(bcnt[b], 1.0f);
#pragma unroll
        for (int c = 0; c < 32; c++) {
            avg[c] = bsum[b * 32 + c] * inv;
            mx[c]  = __uint_as_float(bmax[b * 32 + c]);
            o[c] = 0.f;
        }
#pragma unroll
        for (int pass = 0; pass < 2; pass++) {
            float r[8];
#pragma unroll
            for (int j = 0; j < 8; j++) {
                float s = cab1[j];
#pragma unroll
                for (int c = 0; c < 32; c++) s += (pass ? mx[c] : avg[c]) * caw1[c * 8 + j];
                r[j] = fmaxf(s, 0.f);
            }
#pragma unroll
            for (int d = 0; d < 32; d++) {
                float s = cab2[d];
#pragma unroll
                for (int j = 0; j < 8; j++) s += r[j] * caw2[j * 32 + d];
                o[d] += s;
            }
        }
#pragma unroll
        for (int d = 0; d < 32; d++)
            cas[b * 32 + d] = 1.0f / (1.0f + expf(-o[d]));
    }
    __syncthreads();
    int t = blockIdx.x * 256 + threadIdx.x;
    int v = t >> 1, hf = t & 1;
    if (v >= NVOX) return;
    int b = vb[v];
    float4* hp = (float4*)(h2 + (size_t)v * 32) + hf * 4;
    const float4* cp = (const float4*)(cas + b * 32) + hf * 4;
    float sum = 0.f, mx = 0.f;
#pragma unroll
    for (int q = 0; q < 4; q++) {
        float4 h = hp[q]; float4 c = cp[q];
        h.x *= c.x; h.y *= c.y; h.z *= c.z; h.w *= c.w;
        hp[q] = h;
        sum += h.x + h.y + h.z + h.w;
        mx = fmaxf(mx, fmaxf(fmaxf(h.x, h.y), fmaxf(h.z, h.w)));
    }
    sum += __shfl_xor(sum, 1);
    mx = fmaxf(mx, __shfl_xor(mx, 1));
    if (hf == 0) {
        s2[v * 2 + 0] = sum * (1.0f / 32.0f);
        s2[v * 2 + 1] = mx;
    }
}

// ---- spatial attention: 2-ch sparse conv -> sigmoid; 4 thr/voxel ----
__global__ void k_saconv(const float* __restrict__ s2, const float* __restrict__ saW,
                         const int* __restrict__ nidx, const void* __restrict__ nmask,
                         const int* __restrict__ flag, float* __restrict__ sa) {
    __shared__ float w[KK * 2];
    if (threadIdx.x < KK * 2) w[threadIdx.x] = saW[threadIdx.x];
    __syncthreads();
    int t = blockIdx.x * 256 + threadIdx.x;
    int v = t >> 2, q = t & 3;
    if (v >= NVOX) return;
    int fl = *flag;
    float acc = 0.f;
#pragma unroll
    for (int j = 0; j < 7; j++) {
        int k = q + j * 4;
        if (k < KK) {
            int idx = nidx[k * NVOX + v];
            float m = get_mask(nmask, fl, (long)k * NVOX + v);
            float2 s = ((const float2*)s2)[idx];
            acc += m * (s.x * w[k * 2] + s.y * w[k * 2 + 1]);
        }
    }
    acc += __shfl_xor(acc, 1);
    acc += __shfl_xor(acc, 2);
    if (q == 0) sa[v] = 1.0f / (1.0f + expf(-acc));
}

// ---- gather to points, apply sa, classifier; 2 thr/point; coalesced stores ----
__global__ __launch_bounds__(256) void k_final(
        const float* __restrict__ h2, const float* __restrict__ sa,
        const int* __restrict__ p2v, const float* __restrict__ clsw,
        const float* __restrict__ clsb, float* __restrict__ out) {
    __shared__ float w[32 * 20];
    __shared__ float bb[20];
    for (int i = threadIdx.x; i < 640; i += 256) w[i] = clsw[i];
    if (threadIdx.x < 20) bb[threadIdx.x] = clsb[threadIdx.x];
    __syncthreads();
    int t = blockIdx.x * 256 + threadIdx.x;
    int p = t >> 1, ch = t & 1;
    if (p >= NPTS) return;
    int v = p2v[p];
    float s = sa[v];
    float acc[20];
#pragma unroll
    for (int j = 0; j < 20; j++) acc[j] = 0.f;
    const float4* hp = (const float4*)(h2 + (size_t)v * 32) + ch * 4;
#pragma unroll
    for (int q = 0; q < 4; q++) {
        float4 h = hp[q];
        int cb = (ch * 16 + q * 4) * 20;
        float z0 = h.x * s, z1 = h.y * s, z2 = h.z * s, z3 = h.w * s;
#pragma unroll
        for (int j = 0; j < 20; j++)
            acc[j] += z0 * w[cb + j] + z1 * w[cb + 20 + j]
                    + z2 * w[cb + 40 + j] + z3 * w[cb + 60 + j];
    }
#pragma unroll
    for (int j = 0; j < 20; j++) acc[j] += __shfl_xor(acc[j], 1);
    // both lanes hold the full sums: each stores its own 10 contiguous floats
    float* op = out + (size_t)p * 20;
    if (ch == 0) {
#pragma unroll
        for (int j = 0; j < 5; j++)
            ((float2*)op)[j] = make_float2(acc[2 * j] + bb[2 * j],
                                           acc[2 * j + 1] + bb[2 * j + 1]);
    } else {
#pragma unroll
        for (int j = 0; j < 5; j++)
            ((float2*)(op + 10))[j] = make_float2(acc[10 + 2 * j] + bb[10 + 2 * j],
                                                  acc[11 + 2 * j] + bb[11 + 2 * j]);
    }
}

extern "C" void kernel_launch(void* const* d_in, const int* in_sizes, int n_in,
                              void* d_out, int out_size, void* d_ws, size_t ws_size,
                              hipStream_t stream) {
    const float* feat = (const float*)d_in[0];
    const float* W1   = (const float*)d_in[1];
    const float* g1   = (const float*)d_in[2];
    const float* b1   = (const float*)d_in[3];
    const float* W2   = (const float*)d_in[4];
    const float* g2   = (const float*)d_in[5];
    const float* b2   = (const float*)d_in[6];
    const float* caw1 = (const float*)d_in[7];
    const float* cab1 = (const float*)d_in[8];
    const float* caw2 = (const float*)d_in[9];
    const float* cab2 = (const float*)d_in[10];
    const float* saW  = (const float*)d_in[11];
    const float* clsw = (const float*)d_in[12];
    const float* clsb = (const float*)d_in[13];
    const int* p2v    = (const int*)d_in[14];
    const int* vb     = (const int*)d_in[15];
    const int* nidx   = (const int*)d_in[16];
    const void* nmask = d_in[17];
    float* out = (float*)d_out;

    int* flag   = (int*)d_ws;
    float* cnt  = (float*)d_ws + 64;              // 60000
    __half2* voxh = (__half2*)(cnt + NVOX);       // NVOX*2 half2 = 120000 f32-slots
    float* vox  = (float*)(voxh) + NVOX * 2;      // f32 averages (240000)
    float* bsum = vox + (size_t)NVOX * 4;         // 128
    unsigned int* bmax = (unsigned int*)(bsum + NB * 32);  // 128
    float* bcnt = (float*)(bmax + NB * 32);       // 4
    float* ca   = bcnt + 64;                      // 128 (layout pad)
    unsigned* W2tb = (unsigned*)(ca + 128);       // 13824 u32 bf16 W2^T (+pad)
    unsigned* h1b = W2tb + 14336;                 // bf16-packed h1: NVOX*16 uints
    float* h2   = (float*)(h1b + (size_t)NVOX * 16);
    float* s2   = h2 + (size_t)NVOX * 32;
    float* sa   = s2 + (size_t)NVOX * 2;

    // zero cnt + voxh + (vox) + bsum/bmax/bcnt/ca region
    int nzero = NVOX * 7 + NB * 32 * 2 + NB + 64;
    k_init<<<512, 256, 0, stream>>>(cnt, nzero, (const unsigned int*)nmask, flag, W2, W2tb);
    k_scatter<<<(NPTS + 255) / 256, 256, 0, stream>>>((const float4*)feat, p2v, cnt, voxh);
    k_voxdiv<<<(NVOX + 255) / 256, 256, 0, stream>>>(voxh, vox, cnt);
    k_conv1<<<(NVOX + 63) / 64, 256, 0, stream>>>(vox, W1, g1, b1, nidx, nmask, flag, h1b);
    k_conv2<<<(NTILE + 1) / 2, 512, 0, stream>>>(h1b, W2tb, g2, b2, nidx, nmask,
                                                 flag, h2, vb, bsum, bmax, bcnt);
    k_apply<<<(NVOX * 2 + 255) / 256, 256, 0, stream>>>(h2, bsum, bmax, bcnt,
                                                        caw1, cab1, caw2, cab2, vb, s2);
    k_saconv<<<(NVOX * 4 + 255) / 256, 256, 0, stream>>>(s2, saW, nidx, nmask, flag, sa);
    k_final<<<(NPTS * 2 + 255) / 256, 256, 0, stream>>>(h2, sa, p2v, clsw, clsb, out);
}

// Round 27
// 170.765 us; speedup vs baseline: 1.0832x; 1.0096x over previous
//
#include <hip/hip_runtime.h>
#include <hip/hip_bf16.h>
#include <hip/hip_fp16.h>

#define NPTS 200000
#define NVOX 60000
#define NB 4
#define KK 27
#define NTILE 1875          // NVOX/32
#define TPB 2               // tiles per block in k_conv2

typedef short bf16x8 __attribute__((ext_vector_type(8)));
typedef float f32x4 __attribute__((ext_vector_type(4)));

__device__ __forceinline__ bf16x8 as_bf16x8(uint4 u) {
    union { uint4 a; bf16x8 b; } x; x.a = u; return x.b;
}

// ---- mask encoding: 0 = uint8 bool, 1 = int32, 2 = float32 ----
__device__ __forceinline__ float get_mask(const void* nm, int fl, long i) {
    if (fl == 0) return ((const unsigned char*)nm)[i] ? 1.0f : 0.0f;
    if (fl == 1) return ((const int*)nm)[i] ? 1.0f : 0.0f;
    return ((const float*)nm)[i];
}

// bf16 helpers: RNE pack
__device__ __forceinline__ unsigned bf16rn(float f) {
    unsigned u = __float_as_uint(f);
    u += 0x7fffu + ((u >> 16) & 1u);
    return u >> 16;
}

// ---- init: zero scratch + pack W2 -> bf16 TRANSPOSED [k][cout][cin] + detect mask ----
__global__ void k_init(float* zbase, int nz, const unsigned int* nm, int* flag,
                       const float* __restrict__ W2, unsigned* __restrict__ W2tb) {
    int t0 = blockIdx.x * 256 + threadIdx.x;
    for (int i = t0; i < nz; i += gridDim.x * 256)
        zbase[i] = 0.f;
    // W2tb[k*512 + n*16 + c/2] = bf16(W2[k][c][n]) | bf16(W2[k][c+1][n])<<16
    for (int i = t0; i < KK * 512; i += gridDim.x * 256) {
        int k = i >> 9, r = i & 511, n = r >> 4, cp = r & 15;
        const float* wsrc = W2 + k * 1024;
        unsigned lo = bf16rn(wsrc[(2 * cp) * 32 + n]);
        unsigned hi = bf16rn(wsrc[(2 * cp + 1) * 32 + n]);
        W2tb[i] = lo | (hi << 16);
    }
    if (blockIdx.x == 0) {
        __shared__ int cntF, cntI;
        if (threadIdx.x == 0) { cntF = 0; cntI = 0; }
        __syncthreads();
        int f = 0, i1 = 0;
        for (int i = threadIdx.x; i < 1024; i += 256) {
            unsigned int v = nm[i];
            if (v == 0x3f800000u) f++;
            if (v == 1u) i1++;
        }
        atomicAdd(&cntF, f); atomicAdd(&cntI, i1);
        __syncthreads();
        if (threadIdx.x == 0)
            *flag = (cntF > 100) ? 2 : ((cntI > 100) ? 1 : 0);
    }
}

// ---- voxelize: scatter-add via packed-f16 atomics (3 atomics/point) ----
__global__ void k_scatter(const float4* __restrict__ feat, const int* __restrict__ p2v,
                          float* cnt, __half2* voxh) {
    int p = blockIdx.x * 256 + threadIdx.x;
    if (p >= NPTS) return;
    int v = p2v[p];
    float4 f = feat[p];
    atomicAdd(&cnt[v], 1.0f);
    unsafeAtomicAdd(&voxh[v * 2 + 0], __floats2half2_rn(f.x, f.y));
    unsafeAtomicAdd(&voxh[v * 2 + 1], __floats2half2_rn(f.z, f.w));
}

// ---- voxdiv: f16 sums -> f32 averages ----
__global__ void k_voxdiv(const __half2* __restrict__ voxh, float* vox,
                         const float* __restrict__ cnt) {
    int n = blockIdx.x * 256 + threadIdx.x;
    if (n >= NVOX) return;
    float inv = 1.0f / fmaxf(cnt[n], 1.0f);
    float2 ab = __half22float2(voxh[n * 2 + 0]);
    float2 cd = __half22float2(voxh[n * 2 + 1]);
    float4 v = make_float4(ab.x * inv, ab.y * inv, cd.x * inv, cd.y * inv);
    ((float4*)vox)[n] = v;
}

// ---- conv1: Cin=4 -> Cout=32; 256 thr = 64 vox x 4 kc-waves; h1 OUT in bf16 ----
__global__ __launch_bounds__(256) void k_conv1(
        const float* __restrict__ vox, const float* __restrict__ W1,
        const float* __restrict__ g1, const float* __restrict__ b1,
        const int* __restrict__ nidx, const void* __restrict__ nmask,
        const int* __restrict__ flag, unsigned* __restrict__ h1b) {
    __shared__ float part[3][64][33];
    int tid = threadIdx.x;
    int lane = tid & 63;
    int kc = __builtin_amdgcn_readfirstlane(tid >> 6);   // wave-uniform chunk
    int v = blockIdx.x * 64 + lane;
    int vc = v < NVOX ? v : NVOX - 1;
    int fl = *flag;
    int k0 = kc * 7;
    int k1 = (kc == 3) ? KK : k0 + 7;   // 7,7,7,6
    float acc[32];
#pragma unroll
    for (int d = 0; d < 32; d++) acc[d] = 0.f;
#pragma unroll 2
    for (int k = k0; k < k1; ++k) {
        int idx = nidx[k * NVOX + vc];
        float m = get_mask(nmask, fl, (long)k * NVOX + vc);
        float4 r = ((const float4*)vox)[idx];
        const float* wk = W1 + k * 128;   // wave-uniform -> s_load (3.4KB, K$-resident)
#pragma unroll
        for (int c = 0; c < 4; c++) {
            float rc = (c == 0 ? r.x : c == 1 ? r.y : c == 2 ? r.z : r.w) * m;
            const float* wc = wk + c * 32;
#pragma unroll
            for (int d = 0; d < 32; d++) acc[d] = fmaf(rc, wc[d], acc[d]);
        }
    }
    if (kc > 0) {
#pragma unroll
        for (int d = 0; d < 32; d++) part[kc - 1][lane][d] = acc[d];
    }
    __syncthreads();
    if (kc == 0 && v < NVOX) {
        unsigned pk[16];
#pragma unroll
        for (int i = 0; i < 16; i++) {
            float e0 = acc[2 * i]     + part[0][lane][2 * i]     + part[1][lane][2 * i]     + part[2][lane][2 * i];
            float e1 = acc[2 * i + 1] + part[0][lane][2 * i + 1] + part[1][lane][2 * i + 1] + part[2][lane][2 * i + 1];
            float o0 = fmaxf(e0 * g1[2 * i] + b1[2 * i], 0.f);
            float o1 = fmaxf(e1 * g1[2 * i + 1] + b1[2 * i + 1], 0.f);
            pk[i] = bf16rn(o0) | (bf16rn(o1) << 16);
        }
        uint4* op = (uint4*)(h1b + (size_t)v * 16);   // 64B row
#pragma unroll
        for (int qq = 0; qq < 4; qq++)
            op[qq] = make_uint4(pk[qq * 4], pk[qq * 4 + 1], pk[qq * 4 + 2], pk[qq * 4 + 3]);
    }
}

// ---- conv2 via MFMA: r24 best configuration (54us; 7 structures tried, floor) ----
// 256 thr = 4 waves = 2 vox-tiles(16) x 2 kc halves; TPB=2; preload-pipeline.
__global__ __launch_bounds__(256) void k_conv2(
        const unsigned* __restrict__ h1b, const unsigned* __restrict__ W2tb,
        const float* __restrict__ g2, const float* __restrict__ b2,
        const int* __restrict__ nidx, const void* __restrict__ nmask,
        const int* __restrict__ flag, float* __restrict__ h2,
        const int* __restrict__ vb,
        float* bsum, unsigned int* bmax, float* bcnt) {
    __shared__ float part[2][64][8];   // kc=1 partials, 4KB (reused per tile)
    __shared__ float ls[NB * 32];
    __shared__ unsigned lm[NB * 32];
    __shared__ float lc[NB];
    int tid = threadIdx.x;
    if (tid < NB * 32) { ls[tid] = 0.f; lm[tid] = 0u; }
    if (tid < NB) lc[tid] = 0.f;
    __syncthreads();
    int l = tid & 63;
    int w = tid >> 6;
    int t  = __builtin_amdgcn_readfirstlane(w & 1);    // vox tile half
    int kc = __builtin_amdgcn_readfirstlane(w >> 1);   // k half
    int col = l & 15;                                  // cout (and A vox row)
    int kgrp = l >> 4;                                 // cin slice
    int fl = *flag;
    int k0 = kc ? 14 : 0;
    int k1 = kc ? KK : 14;   // 13 or 14 valid iterations

#pragma unroll 1
    for (int tile = 0; tile < TPB; ++tile) {
        int ti = blockIdx.x * TPB + tile;
        bool active = ti < NTILE;                      // block-uniform
        int vbase = ti * 32 + t * 16;
        int vrow = vbase + col;
        f32x4 acc0 = {0.f, 0.f, 0.f, 0.f};
        f32x4 acc1 = {0.f, 0.f, 0.f, 0.f};
        if (active) {
            // Phase 1: preload all k indices (independent loads, one latency)
            int pidx[14];
#pragma unroll
            for (int j = 0; j < 14; ++j) {
                int k = k0 + j;
                bool ok = k < k1;
                int kk = ok ? k : k0;
                int idx = nidx[kk * NVOX + vrow];
                float m = get_mask(nmask, fl, (long)kk * NVOX + vrow);
                pidx[j] = (ok && m != 0.f) ? idx : -1;
            }
            // Phase 2: register-indexed gathers + MFMA (chains independent)
#pragma unroll
            for (int j = 0; j < 14; ++j) {
                int pi = pidx[j];
                uint4 a = make_uint4(0u, 0u, 0u, 0u);
                if (pi >= 0)
                    a = ((const uint4*)(h1b + (size_t)pi * 16))[kgrp];
                int kw = (k0 + j < KK) ? (k0 + j) : 0;   // clamp: no garbage B
                const uint4* wt = (const uint4*)(W2tb + kw * 512);
                uint4 bA = wt[col * 4 + kgrp];          // cout = col
                uint4 bB = wt[(col + 16) * 4 + kgrp];   // cout = col+16
                bf16x8 av = as_bf16x8(a);
                acc0 = __builtin_amdgcn_mfma_f32_16x16x32_bf16(av, as_bf16x8(bA), acc0, 0, 0, 0);
                acc1 = __builtin_amdgcn_mfma_f32_16x16x32_bf16(av, as_bf16x8(bB), acc1, 0, 0, 0);
            }
            if (kc == 1) {
#pragma unroll
                for (int r = 0; r < 4; r++) {
                    part[t][l][r]     = acc0[r];
                    part[t][l][4 + r] = acc1[r];
                }
            }
        }
        __syncthreads();
        if (active && kc == 0) {
#pragma unroll
            for (int r = 0; r < 4; r++) {
                acc0[r] += part[t][l][r];
                acc1[r] += part[t][l][4 + r];
            }
            float ga = g2[col],      ba = b2[col];
            float gb = g2[col + 16], bb_ = b2[col + 16];
#pragma unroll
            for (int r = 0; r < 4; r++) {
                int vox = vbase + kgrp * 4 + r;
                float o0 = fmaxf(acc0[r] * ga + ba, 0.f);
                float o1 = fmaxf(acc1[r] * gb + bb_, 0.f);
                h2[(size_t)vox * 32 + col]      = o0;
                h2[(size_t)vox * 32 + 16 + col] = o1;
                int b = vb[vox];
                atomicAdd(&ls[b * 32 + col], o0);
                atomicAdd(&ls[b * 32 + 16 + col], o1);
                atomicMax(&lm[b * 32 + col], __float_as_uint(o0));       // o >= 0
                atomicMax(&lm[b * 32 + 16 + col], __float_as_uint(o1));
                if (col == 0) atomicAdd(&lc[b], 1.f);
            }
        }
        __syncthreads();   // part[] safe for next tile
    }
    if (tid < NB * 32) {
        atomicAdd(&bsum[tid], ls[tid]);
        atomicMax(&bmax[tid], lm[tid]);
    }
    if (tid < NB) atomicAdd(&bcnt[tid], lc[tid]);
}

// ---- apply channel attention + build s2; CA-MLP fused ----
__global__ void k_apply(float* h2,
                        const float* __restrict__ bsum, const unsigned int* __restrict__ bmax,
                        const float* __restrict__ bcnt,
                        const float* __restrict__ caw1, const float* __restrict__ cab1,
                        const float* __restrict__ caw2, const float* __restrict__ cab2,
                        const int* __restrict__ vb, float* __restrict__ s2) {
    __shared__ float cas[NB * 32];
    if (threadIdx.x < NB) {
        int b = threadIdx.x;
        float avg[32], mx[32], o[32];
        float inv = 1.0f / fmaxf(bcnt[b], 1.0f);
#pragma unroll
        for (int c = 0; c < 32; c++) {
            avg[c] = bsum[b * 32 + c] * inv;
            mx[c]  = __uint_as_float(bmax[b * 32 + c]);
            o[c] = 0.f;
        }
#pragma unroll
        for (int pass = 0; pass < 2; pass++) {
            float r[8];
#pragma unroll
            for (int j = 0; j < 8; j++) {
                float s = cab1[j];
#pragma unroll
                for (int c = 0; c < 32; c++) s += (pass ? mx[c] : avg[c]) * caw1[c * 8 + j];
                r[j] = fmaxf(s, 0.f);
            }
#pragma unroll
            for (int d = 0; d < 32; d++) {
                float s = cab2[d];
#pragma unroll
                for (int j = 0; j < 8; j++) s += r[j] * caw2[j * 32 + d];
                o[d] += s;
            }
        }
#pragma unroll
        for (int d = 0; d < 32; d++)
            cas[b * 32 + d] = 1.0f / (1.0f + expf(-o[d]));
    }
    __syncthreads();
    int t = blockIdx.x * 256 + threadIdx.x;
    int v = t >> 1, hf = t & 1;
    if (v >= NVOX) return;
    int b = vb[v];
    float4* hp = (float4*)(h2 + (size_t)v * 32) + hf * 4;
    const float4* cp = (const float4*)(cas + b * 32) + hf * 4;
    float sum = 0.f, mx = 0.f;
#pragma unroll
    for (int q = 0; q < 4; q++) {
        float4 h = hp[q]; float4 c = cp[q];
        h.x *= c.x; h.y *= c.y; h.z *= c.z; h.w *= c.w;
        hp[q] = h;
        sum += h.x + h.y + h.z + h.w;
        mx = fmaxf(mx, fmaxf(fmaxf(h.x, h.y), fmaxf(h.z, h.w)));
    }
    sum += __shfl_xor(sum, 1);
    mx = fmaxf(mx, __shfl_xor(mx, 1));
    if (hf == 0) {
        s2[v * 2 + 0] = sum * (1.0f / 32.0f);
        s2[v * 2 + 1] = mx;
    }
}

// ---- spatial attention: 2-ch sparse conv -> sigmoid; 4 thr/voxel ----
__global__ void k_saconv(const float* __restrict__ s2, const float* __restrict__ saW,
                         const int* __restrict__ nidx, const void* __restrict__ nmask,
                         const int* __restrict__ flag, float* __restrict__ sa) {
    __shared__ float w[KK * 2];
    if (threadIdx.x < KK * 2) w[threadIdx.x] = saW[threadIdx.x];
    __syncthreads();
    int t = blockIdx.x * 256 + threadIdx.x;
    int v = t >> 2, q = t & 3;
    if (v >= NVOX) return;
    int fl = *flag;
    float acc = 0.f;
#pragma unroll
    for (int j = 0; j < 7; j++) {
        int k = q + j * 4;
        if (k < KK) {
            int idx = nidx[k * NVOX + v];
            float m = get_mask(nmask, fl, (long)k * NVOX + v);
            float2 s = ((const float2*)s2)[idx];
            acc += m * (s.x * w[k * 2] + s.y * w[k * 2 + 1]);
        }
    }
    acc += __shfl_xor(acc, 1);
    acc += __shfl_xor(acc, 2);
    if (q == 0) sa[v] = 1.0f / (1.0f + expf(-acc));
}

// ---- gather to points, apply sa, classifier; 2 thr/point; coalesced stores ----
__global__ __launch_bounds__(256) void k_final(
        const float* __restrict__ h2, const float* __restrict__ sa,
        const int* __restrict__ p2v, const float* __restrict__ clsw,
        const float* __restrict__ clsb, float* __restrict__ out) {
    __shared__ float w[32 * 20];
    __shared__ float bb[20];
    for (int i = threadIdx.x; i < 640; i += 256) w[i] = clsw[i];
    if (threadIdx.x < 20) bb[threadIdx.x] = clsb[threadIdx.x];
    __syncthreads();
    int t = blockIdx.x * 256 + threadIdx.x;
    int p = t >> 1, ch = t & 1;
    if (p >= NPTS) return;
    int v = p2v[p];
    float s = sa[v];
    float acc[20];
#pragma unroll
    for (int j = 0; j < 20; j++) acc[j] = 0.f;
    const float4* hp = (const float4*)(h2 + (size_t)v * 32) + ch * 4;
#pragma unroll
    for (int q = 0; q < 4; q++) {
        float4 h = hp[q];
        int cb = (ch * 16 + q * 4) * 20;
        float z0 = h.x * s, z1 = h.y * s, z2 = h.z * s, z3 = h.w * s;
#pragma unroll
        for (int j = 0; j < 20; j++)
            acc[j] += z0 * w[cb + j] + z1 * w[cb + 20 + j]
                    + z2 * w[cb + 40 + j] + z3 * w[cb + 60 + j];
    }
#pragma unroll
    for (int j = 0; j < 20; j++) acc[j] += __shfl_xor(acc[j], 1);
    // both lanes hold the full sums: each stores its own 10 contiguous floats
    float* op = out + (size_t)p * 20;
    if (ch == 0) {
#pragma unroll
        for (int j = 0; j < 5; j++)
            ((float2*)op)[j] = make_float2(acc[2 * j] + bb[2 * j],
                                           acc[2 * j + 1] + bb[2 * j + 1]);
    } else {
#pragma unroll
        for (int j = 0; j < 5; j++)
            ((float2*)(op + 10))[j] = make_float2(acc[10 + 2 * j] + bb[10 + 2 * j],
                                                  acc[11 + 2 * j] + bb[11 + 2 * j]);
    }
}

extern "C" void kernel_launch(void* const* d_in, const int* in_sizes, int n_in,
                              void* d_out, int out_size, void* d_ws, size_t ws_size,
                              hipStream_t stream) {
    const float* feat = (const float*)d_in[0];
    const float* W1   = (const float*)d_in[1];
    const float* g1   = (const float*)d_in[2];
    const float* b1   = (const float*)d_in[3];
    const float* W2   = (const float*)d_in[4];
    const float* g2   = (const float*)d_in[5];
    const float* b2   = (const float*)d_in[6];
    const float* caw1 = (const float*)d_in[7];
    const float* cab1 = (const float*)d_in[8];
    const float* caw2 = (const float*)d_in[9];
    const float* cab2 = (const float*)d_in[10];
    const float* saW  = (const float*)d_in[11];
    const float* clsw = (const float*)d_in[12];
    const float* clsb = (const float*)d_in[13];
    const int* p2v    = (const int*)d_in[14];
    const int* vb     = (const int*)d_in[15];
    const int* nidx   = (const int*)d_in[16];
    const void* nmask = d_in[17];
    float* out = (float*)d_out;

    int* flag   = (int*)d_ws;
    float* cnt  = (float*)d_ws + 64;              // 60000
    __half2* voxh = (__half2*)(cnt + NVOX);       // NVOX*2 half2 = 120000 f32-slots
    float* vox  = (float*)(voxh) + NVOX * 2;      // f32 averages (240000)
    float* bsum = vox + (size_t)NVOX * 4;         // 128
    unsigned int* bmax = (unsigned int*)(bsum + NB * 32);  // 128
    float* bcnt = (float*)(bmax + NB * 32);       // 4
    float* ca   = bcnt + 64;                      // 128 (layout pad)
    unsigned* W2tb = (unsigned*)(ca + 128);       // 13824 u32 bf16 W2^T (+pad)
    unsigned* h1b = W2tb + 14336;                 // bf16-packed h1: NVOX*16 uints
    float* h2   = (float*)(h1b + (size_t)NVOX * 16);
    float* s2   = h2 + (size_t)NVOX * 32;
    float* sa   = s2 + (size_t)NVOX * 2;

    // zero cnt + voxh + (vox) + bsum/bmax/bcnt/ca region
    int nzero = NVOX * 7 + NB * 32 * 2 + NB + 64;
    k_init<<<512, 256, 0, stream>>>(cnt, nzero, (const unsigned int*)nmask, flag, W2, W2tb);
    k_scatter<<<(NPTS + 255) / 256, 256, 0, stream>>>((const float4*)feat, p2v, cnt, voxh);
    k_voxdiv<<<(NVOX + 255) / 256, 256, 0, stream>>>(voxh, vox, cnt);
    k_conv1<<<(NVOX + 63) / 64, 256, 0, stream>>>(vox, W1, g1, b1, nidx, nmask, flag, h1b);
    k_conv2<<<(NTILE + TPB - 1) / TPB, 256, 0, stream>>>(h1b, W2tb, g2, b2, nidx, nmask,
                                                         flag, h2, vb, bsum, bmax, bcnt);
    k_apply<<<(NVOX * 2 + 255) / 256, 256, 0, stream>>>(h2, bsum, bmax, bcnt,
                                                        caw1, cab1, caw2, cab2, vb, s2);
    k_saconv<<<(NVOX * 4 + 255) / 256, 256, 0, stream>>>(s2, saW, nidx, nmask, flag, sa);
    k_final<<<(NPTS * 2 + 255) / 256, 256, 0, stream>>>(h2, sa, p2v, clsw, clsb, out);
}